// Round 1
// baseline (416.047 us; speedup 1.0000x reference)
//
#include <hip/hip_runtime.h>

#define H 12
#define S 2048
#define D 768
#define HD 64
#define BATCH 4
#define M_TOT (BATCH * S)   // 8192

typedef __attribute__((ext_vector_type(8))) short bf16x8;
typedef __attribute__((ext_vector_type(4))) float f32x4;

__device__ __forceinline__ ushort f2bf(float f) {
  unsigned int x = __float_as_uint(f);
  x += 0x7fffu + ((x >> 16) & 1u);
  return (ushort)(x >> 16);
}

// ---------------- cast fp32 -> bf16, vectorized x4 ----------------
__global__ __launch_bounds__(256) void cast_kernel(const float* __restrict__ src,
                                                   ushort* __restrict__ dst, int n4) {
  int i = blockIdx.x * blockDim.x + threadIdx.x;
  if (i >= n4) return;
  float4 f = reinterpret_cast<const float4*>(src)[i];
  ushort4 u;
  u.x = f2bf(f.x); u.y = f2bf(f.y); u.z = f2bf(f.z); u.w = f2bf(f.w);
  reinterpret_cast<ushort4*>(dst)[i] = u;
}

// ---------------- GEMM: Y[m,n] = sum_k A[m,k] * W[n,k] ----------------
// A: [M_TOT x 768] bf16 row-major, W: [768 x 768] bf16 row-major (torch Linear weight)
// mode 0: store bf16 into QKV layout [b][h][s][hd]
// mode 1: store fp32 + bias into out [m][n]
__global__ __launch_bounds__(256) void gemm_bt(const ushort* __restrict__ A,
                                               const ushort* __restrict__ W,
                                               ushort* __restrict__ out_bf,
                                               float* __restrict__ out_f,
                                               const float* __restrict__ bias,
                                               int mode) {
  __shared__ ushort As[64][40];  // 40-ushort stride = 80B, 16B-aligned, bank-spread
  __shared__ ushort Ws[64][40];
  const int tid = threadIdx.x;
  const int lane = tid & 63, wid = tid >> 6;
  const int g = lane >> 4, li = lane & 15;
  const int wm = wid >> 1, wn = wid & 1;
  const int m0 = blockIdx.x * 64, n0 = blockIdx.y * 64;

  f32x4 acc[2][2] = {};
  const int arow = tid >> 2, ac8 = (tid & 3) * 8;

  for (int k0 = 0; k0 < 768; k0 += 32) {
    __syncthreads();
    *reinterpret_cast<bf16x8*>(&As[arow][ac8]) =
        *reinterpret_cast<const bf16x8*>(&A[(size_t)(m0 + arow) * 768 + k0 + ac8]);
    *reinterpret_cast<bf16x8*>(&Ws[arow][ac8]) =
        *reinterpret_cast<const bf16x8*>(&W[(size_t)(n0 + arow) * 768 + k0 + ac8]);
    __syncthreads();
    bf16x8 a0 = *reinterpret_cast<const bf16x8*>(&As[wm * 32 + li][g * 8]);
    bf16x8 a1 = *reinterpret_cast<const bf16x8*>(&As[wm * 32 + 16 + li][g * 8]);
    bf16x8 b0 = *reinterpret_cast<const bf16x8*>(&Ws[wn * 32 + li][g * 8]);
    bf16x8 b1 = *reinterpret_cast<const bf16x8*>(&Ws[wn * 32 + 16 + li][g * 8]);
    acc[0][0] = __builtin_amdgcn_mfma_f32_16x16x32_bf16(a0, b0, acc[0][0], 0, 0, 0);
    acc[0][1] = __builtin_amdgcn_mfma_f32_16x16x32_bf16(a0, b1, acc[0][1], 0, 0, 0);
    acc[1][0] = __builtin_amdgcn_mfma_f32_16x16x32_bf16(a1, b0, acc[1][0], 0, 0, 0);
    acc[1][1] = __builtin_amdgcn_mfma_f32_16x16x32_bf16(a1, b1, acc[1][1], 0, 0, 0);
  }

  for (int i = 0; i < 2; ++i)
    for (int j = 0; j < 2; ++j)
      for (int r = 0; r < 4; ++r) {
        int m = m0 + wm * 32 + i * 16 + g * 4 + r;  // C row = (lane>>4)*4 + reg
        int n = n0 + wn * 32 + j * 16 + li;         // C col = lane&15
        float v = acc[i][j][r];
        if (mode == 0) {
          int b = m >> 11, s = m & 2047;  // S = 2048
          int h = n >> 6, hd = n & 63;    // HD = 64
          out_bf[(((size_t)b * H + h) * S + s) * HD + hd] = f2bf(v);
        } else {
          out_f[(size_t)m * 768 + n] = v + bias[n];
        }
      }
}

// ---------------- flash attention (causal) ----------------
// Q,K,V: [b][h][s][hd] bf16. ctx out: [b][s][h*64+hd] bf16.
__global__ __launch_bounds__(256) void attn_kernel(const ushort* __restrict__ Q,
                                                   const ushort* __restrict__ K,
                                                   const ushort* __restrict__ V,
                                                   ushort* __restrict__ ctx) {
  __shared__ ushort Ks[32][72];      // K tile rows, contiguous in d; 144B stride
  __shared__ ushort Vt[64][40];      // V transposed: Vt[d][k]; 80B stride
  __shared__ ushort Ps[4][16][40];   // per-wave P tile for layout conversion

  const int tid = threadIdx.x;
  const int lane = tid & 63, wid = tid >> 6;
  const int g = lane >> 4, li = lane & 15;
  const int q0 = blockIdx.x * 64;
  const int bh = blockIdx.y;  // b*H + h
  const size_t base = (size_t)bh * S * HD;

  // Q A-fragments: rows q0 + wid*16 + li, k (=d) split into two 32-chunks
  const size_t qrow = base + (size_t)(q0 + wid * 16 + li) * HD;
  bf16x8 aq0 = *reinterpret_cast<const bf16x8*>(&Q[qrow + g * 8]);
  bf16x8 aq1 = *reinterpret_cast<const bf16x8*>(&Q[qrow + 32 + g * 8]);

  f32x4 acc[4] = {};
  float m_run[4], l_run[4];
  for (int r = 0; r < 4; ++r) { m_run[r] = -1e30f; l_run[r] = 0.f; }

  const int srow = tid >> 3, sc8 = (tid & 7) * 8;
  const int nkt = q0 / 32 + 2;

  for (int kt = 0; kt < nkt; ++kt) {
    const int k0 = kt * 32;
    __syncthreads();
    // stage K (row-major) and V (transposed)
    bf16x8 kv = *reinterpret_cast<const bf16x8*>(&K[base + (size_t)(k0 + srow) * HD + sc8]);
    *reinterpret_cast<bf16x8*>(&Ks[srow][sc8]) = kv;
    bf16x8 vv = *reinterpret_cast<const bf16x8*>(&V[base + (size_t)(k0 + srow) * HD + sc8]);
#pragma unroll
    for (int j = 0; j < 8; ++j) Vt[sc8 + j][srow] = (ushort)vv[j];
    __syncthreads();

    // scores: QK^T for 16 rows x 32 cols per wave
    f32x4 sc[2];
#pragma unroll
    for (int ct = 0; ct < 2; ++ct) {
      f32x4 z = {};
      bf16x8 kb0 = *reinterpret_cast<const bf16x8*>(&Ks[ct * 16 + li][g * 8]);
      bf16x8 kb1 = *reinterpret_cast<const bf16x8*>(&Ks[ct * 16 + li][32 + g * 8]);
      z = __builtin_amdgcn_mfma_f32_16x16x32_bf16(aq0, kb0, z, 0, 0, 0);
      z = __builtin_amdgcn_mfma_f32_16x16x32_bf16(aq1, kb1, z, 0, 0, 0);
      sc[ct] = z;
    }
#pragma unroll
    for (int ct = 0; ct < 2; ++ct)
#pragma unroll
      for (int r = 0; r < 4; ++r) sc[ct][r] *= 0.125f;  // 1/sqrt(64)
    if (kt >= nkt - 2) {  // only the last two k-tiles can be masked
#pragma unroll
      for (int ct = 0; ct < 2; ++ct)
#pragma unroll
        for (int r = 0; r < 4; ++r)
          if (k0 + ct * 16 + li > q0 + wid * 16 + g * 4 + r) sc[ct][r] = -1e30f;
    }

    // online softmax per row (rows distributed: same row across 16 lanes of a group)
#pragma unroll
    for (int r = 0; r < 4; ++r) {
      float tmax = fmaxf(sc[0][r], sc[1][r]);
      for (int off = 1; off < 16; off <<= 1) tmax = fmaxf(tmax, __shfl_xor(tmax, off));
      float mnew = fmaxf(m_run[r], tmax);
      float corr = __expf(m_run[r] - mnew);
      float p0 = __expf(sc[0][r] - mnew);
      float p1 = __expf(sc[1][r] - mnew);
      float ps = p0 + p1;
      for (int off = 1; off < 16; off <<= 1) ps += __shfl_xor(ps, off);
      l_run[r] = l_run[r] * corr + ps;
      m_run[r] = mnew;
#pragma unroll
      for (int dt = 0; dt < 4; ++dt) acc[dt][r] *= corr;
      Ps[wid][g * 4 + r][li] = f2bf(p0);
      Ps[wid][g * 4 + r][16 + li] = f2bf(p1);
    }

    // PV: A = P (16x32, from per-wave LDS in A-frag layout), B = V (32xd via Vt)
    bf16x8 pa = *reinterpret_cast<const bf16x8*>(&Ps[wid][li][g * 8]);
#pragma unroll
    for (int dt = 0; dt < 4; ++dt) {
      bf16x8 vb = *reinterpret_cast<const bf16x8*>(&Vt[dt * 16 + li][g * 8]);
      acc[dt] = __builtin_amdgcn_mfma_f32_16x16x32_bf16(pa, vb, acc[dt], 0, 0, 0);
    }
  }

  // normalize + store ctx [b][s][h*64+hd]
  const int b = bh / H, h = bh % H;
#pragma unroll
  for (int dt = 0; dt < 4; ++dt)
#pragma unroll
    for (int r = 0; r < 4; ++r) {
      int s = q0 + wid * 16 + g * 4 + r;
      float v = acc[dt][r] / l_run[r];
      ctx[((size_t)(b * S + s)) * D + h * HD + dt * 16 + li] = f2bf(v);
    }
}

extern "C" void kernel_launch(void* const* d_in, const int* in_sizes, int n_in,
                              void* d_out, int out_size, void* d_ws, size_t ws_size,
                              hipStream_t stream) {
  (void)in_sizes; (void)n_in; (void)out_size; (void)ws_size;
  const float* x  = (const float*)d_in[0];
  const float* wq = (const float*)d_in[1];
  const float* wk = (const float*)d_in[2];
  const float* wv = (const float*)d_in[3];
  const float* wo = (const float*)d_in[4];
  const float* bo = (const float*)d_in[5];
  float* out = (float*)d_out;

  const size_t xn = (size_t)M_TOT * D;   // 6291456
  const size_t wn = (size_t)D * D;       // 589824

  ushort* p = (ushort*)d_ws;
  ushort* x_bf  = p; p += xn;
  ushort* wq_bf = p; p += wn;
  ushort* wk_bf = p; p += wn;
  ushort* wv_bf = p; p += wn;
  ushort* wo_bf = p; p += wn;
  ushort* q_bf  = p; p += xn;
  ushort* k_bf  = p; p += xn;
  ushort* v_bf  = p; p += xn;
  ushort* ctx_bf = x_bf;  // alias: x_bf dead after QKV GEMMs, attn writes ctx after

  int n4x = (int)(xn / 4), n4w = (int)(wn / 4);
  cast_kernel<<<(n4x + 255) / 256, 256, 0, stream>>>(x, x_bf, n4x);
  cast_kernel<<<(n4w + 255) / 256, 256, 0, stream>>>(wq, wq_bf, n4w);
  cast_kernel<<<(n4w + 255) / 256, 256, 0, stream>>>(wk, wk_bf, n4w);
  cast_kernel<<<(n4w + 255) / 256, 256, 0, stream>>>(wv, wv_bf, n4w);
  cast_kernel<<<(n4w + 255) / 256, 256, 0, stream>>>(wo, wo_bf, n4w);

  dim3 gg(M_TOT / 64, D / 64);
  gemm_bt<<<gg, 256, 0, stream>>>(x_bf, wq_bf, q_bf, nullptr, nullptr, 0);
  gemm_bt<<<gg, 256, 0, stream>>>(x_bf, wk_bf, k_bf, nullptr, nullptr, 0);
  gemm_bt<<<gg, 256, 0, stream>>>(x_bf, wv_bf, v_bf, nullptr, nullptr, 0);

  dim3 ga(S / 64, BATCH * H);
  attn_kernel<<<ga, 256, 0, stream>>>(q_bf, k_bf, v_bf, ctx_bf);

  gemm_bt<<<gg, 256, 0, stream>>>(ctx_bf, wo_bf, nullptr, out, bo, 1);
}